// Round 1
// baseline (1101.460 us; speedup 1.0000x reference)
//
#include <hip/hip_runtime.h>
#include <math.h>

#define MQ 1000
#define PI_F 3.14159265358979323846f
#define EPSF 1e-12f

// ---------------------------------------------------------------------------
// Coefficients derived from a[2], b[2], logcoef (shared across all elements).
//
// eval_f(a,z) regroups (i,j) pairs by i+j:
//   f(z) = (1 - z^4) + cf1*(z^4 - z) + cf2*(z^4 - z^2) + cf3*(z^4 - z^3)
//          + cf4 * z^4 * ln(z)
//   cf1 = -8 a0/3, cf2 = -2(2 a1 + a0^2), cf3 = -8 a0 a1, cf4 = -4 a1^2
// eval_df(a,z) = (4 f(z) - 4*(1 + e1 z + e2 z^2 + e3 z^3 + e4 z^4)) / z
//   e1 = 2 a0, e2 = 2 a1 + a0^2, e3 = 2 a0 a1, e4 = a1^2
// eval_b_ = P(z)^2 with P(z) = 1 + b0 z + b1 z^2 + p3 z^3, p3 = a0+a1-b0-b1
// g = P^2 / (1 - z^4); dg = 2 P P' /(1-z^4) + 4 z^3 P^2/(1-z^4)^2
// ---------------------------------------------------------------------------
struct Co {
    float b0, b1, p3;
    float cf1, cf2, cf3, cf4;
    float e1, e2, e3, e4;
    float coef;
};

__device__ __forceinline__ Co make_co(const float* a, const float* b, const float* lc) {
    Co c;
    float a0 = a[0], a1 = a[1];
    c.b0 = b[0]; c.b1 = b[1];
    c.cf1 = -8.f * a0 / 3.f;
    c.cf2 = -2.f * (2.f * a1 + a0 * a0);
    c.cf3 = -8.f * a0 * a1;
    c.cf4 = -4.f * a1 * a1;
    c.e1 = 2.f * a0;
    c.e2 = 2.f * a1 + a0 * a0;
    c.e3 = 2.f * a0 * a1;
    c.e4 = a1 * a1;
    c.p3 = a0 + a1 - b[0] - b[1];
    c.coef = expf(lc[0]);
    return c;
}

__device__ __forceinline__ float y_of(int j) {
    // jnp.linspace(0.001, 0.999, 1000): step = 0.998/999
    return 0.001f + (float)j * (float)(0.998 / 999.0);
}

__device__ __forceinline__ float f_of(const Co& c, float z) {
    float z2 = z * z, z3 = z2 * z, z4 = z2 * z2;
    return (1.f - z4) + c.cf1 * (z4 - z) + c.cf2 * (z4 - z2) + c.cf3 * (z4 - z3)
         + c.cf4 * z4 * __logf(z);
}

__device__ __forceinline__ float df_of(const Co& c, float z, float fz) {
    float z2 = z * z;
    float s = 1.f + c.e1 * z + c.e2 * z2 + c.e3 * z2 * z + c.e4 * z2 * z2;
    return (4.f * fz - 4.f * s) / z;
}

__device__ __forceinline__ float g_of(const Co& c, float z) {
    float P = 1.f + z * (c.b0 + z * (c.b1 + z * c.p3));
    float z2 = z * z;
    return P * P / (1.f - z2 * z2);
}

__device__ __forceinline__ void g_dg_of(const Co& c, float z, float& g, float& dg) {
    float P  = 1.f + z * (c.b0 + z * (c.b1 + z * c.p3));
    float dP = c.b0 + z * (2.f * c.b1 + z * (3.f * c.p3));
    float B  = P * P;
    float dB = 2.f * dP * P;
    float z2 = z * z;
    float D  = 1.f - z2 * z2;
    g  = B / D;
    dg = dB / D + 4.f * z * z2 * B / (D * D);
}

// trapz over extended grid yy=[0, y..., 1], ii=[v0, integ..., 0]
// S = sum of all 1000 interior integrand values; i0,i1,iN specific values.
__device__ __forceinline__ float trapz_ext(float S, float i0, float i1, float iN) {
    const float DYF = (float)(0.998 / 999.0);
    float slope = (i1 - i0) / DYF;
    float v0 = i0 - slope * 0.001f;
    float yLast = 0.001f + 999.f * DYF;
    return DYF * (S - 0.5f * (i0 + iN))
         + 0.5f * (v0 + i0) * 0.001f
         + 0.5f * iN * (1.f - yLast);
}

// ---------------------------------------------------------------------------
// Per-point integrands
// ---------------------------------------------------------------------------
__device__ __forceinline__ float integrand_L(const Co& c, float zs, float fs, int j) {
    float y = y_of(j);
    float u = (1.f - y) * (1.f + y);
    float z = zs * u;
    float g = g_of(c, z);
    float fof = f_of(c, z) / fs;
    float u2 = u * u, u4 = u2 * u2;
    float arg = fof / u4 - 1.f;
    return sqrtf(g) / sqrtf(fmaxf(arg, EPSF)) * y;
}

__device__ __forceinline__ void integrands_LdL(const Co& c, float zs, float fs,
                                               float dfs, int j,
                                               float& iL, float& iD) {
    float y = y_of(j);
    float u = (1.f - y) * (1.f + y);
    float z = zs * u;
    float z2 = z * z, z3 = z2 * z, z4 = z2 * z2;
    float fz = f_of(c, z);
    float fof = fz / fs;
    float g, dg;
    g_dg_of(c, z, g, dg);
    float sqg = sqrtf(g);
    // L integrand
    float u2 = u * u, u4 = u2 * u2;
    float argL = fof / u4 - 1.f;
    iL = sqg / sqrtf(fmaxf(argL, EPSF)) * y;
    // dL integrand
    float dfz = df_of(c, z, fz);
    float zs2 = zs * zs, zs4 = zs2 * zs2;
    float zdgg = z * dg / g;
    float r4 = zs4 / z4;
    float t = r4 * fof * (zs * dfs / fs + 2.f + zdgg) - zs4 / z3 * dfz / fs - 2.f - zdgg;
    float den = fmaxf(r4 * fof - 1.f, EPSF);
    float m = 2.f * sqrtf(fmaxf(1.f - z / zs, 0.f)) * sqg / (den * sqrtf(den));
    iD = t * m;
}

__device__ __forceinline__ float integrand_Vc(const Co& c, float zs, float fs, int j) {
    float y = y_of(j);
    float u = (1.f - y) * (1.f + y);
    float z = zs * u;
    float fz = f_of(c, z);
    float g = g_of(c, z);
    float fg = fz * g;
    float fof = fz / fs;
    float w = u * u;
    float w2 = w * w;
    float t = 1.f / sqrtf(fmaxf(1.f - w2 / fof, EPSF)) - 1.f;
    return sqrtf(fmaxf(fg, EPSF)) / w * t * y;
}

__device__ __forceinline__ float integrand_Vd(const Co& c, float zs, int j) {
    // y2 = linspace(0.001, 1.0, 1000): step = 0.999/999 = 0.001
    float y2 = 0.001f + (float)j * 0.001f;
    float z = 1.f - (1.f - zs) * y2;
    float fz = f_of(c, z);
    float g = g_of(c, z);
    return sqrtf(fmaxf(fz * g, EPSF)) / (z * z);
}

// ---------------------------------------------------------------------------
// Kernel 1: scalar bisections (single block, block-wide quadratures)
// ---------------------------------------------------------------------------
__device__ __forceinline__ void block_sum2(float v1, float v2, float* red,
                                           float& s1, float& s2) {
    int lane = threadIdx.x & 63;
    int w = threadIdx.x >> 6;
#pragma unroll
    for (int o = 32; o > 0; o >>= 1) {
        v1 += __shfl_down(v1, o, 64);
        v2 += __shfl_down(v2, o, 64);
    }
    if (lane == 0) { red[w] = v1; red[16 + w] = v2; }
    __syncthreads();
    if (threadIdx.x == 0) {
        float t1 = 0.f, t2 = 0.f;
        for (int i = 0; i < 16; ++i) { t1 += red[i]; t2 += red[16 + i]; }
        red[0] = t1; red[16] = t2;
    }
    __syncthreads();
    s1 = red[0]; s2 = red[16];
    __syncthreads();   // epoch boundary before red/spec reuse
}

__device__ float quad_L_blk(const Co& c, float zs, float* red, float* spec) {
    int j = threadIdx.x;
    float fs = f_of(c, zs);
    float v = (j < MQ) ? integrand_L(c, zs, fs, j) : 0.f;
    if (j == 0) spec[0] = v;
    if (j == 1) spec[1] = v;
    if (j == MQ - 1) spec[2] = v;
    __syncthreads();
    float i0 = spec[0], i1 = spec[1], iN = spec[2];
    float S, dummy;
    block_sum2(v, 0.f, red, S, dummy);
    return 4.f * zs * trapz_ext(S, i0, i1, iN) / PI_F;
}

__device__ float quad_dL_blk(const Co& c, float zs, float* red, float* spec) {
    int j = threadIdx.x;
    float fs = f_of(c, zs);
    float dfs = df_of(c, zs, fs);
    float v = 0.f;
    if (j < MQ) { float iL, iD; integrands_LdL(c, zs, fs, dfs, j, iL, iD); v = iD; }
    if (j == 0) spec[0] = v;
    if (j == 1) spec[1] = v;
    if (j == MQ - 1) spec[2] = v;
    __syncthreads();
    float i0 = spec[0], i1 = spec[1], iN = spec[2];
    float S, dummy;
    block_sum2(v, 0.f, red, S, dummy);
    return trapz_ext(S, i0, i1, iN) / PI_F;
}

__device__ float quad_V_blk(const Co& c, float zs, float* red, float* spec) {
    int j = threadIdx.x;
    float fs = f_of(c, zs);
    float vc = 0.f, vd = 0.f;
    if (j < MQ) { vc = integrand_Vc(c, zs, fs, j); vd = integrand_Vd(c, zs, j); }
    if (j == 0) { spec[0] = vc; spec[3] = vd; }
    if (j == 1) spec[1] = vc;
    if (j == MQ - 1) { spec[2] = vc; spec[4] = vd; }
    __syncthreads();
    float i0 = spec[0], i1 = spec[1], iN = spec[2], q0 = spec[3], qN = spec[4];
    float Sc, Sd;
    block_sum2(vc, vd, red, Sc, Sd);
    float Vc = c.coef * PI_F * 4.f * trapz_ext(Sc, i0, i1, iN) / zs;
    float trd = 0.5f * (1.f + q0) * 0.001f + 0.001f * (Sd - 0.5f * (q0 + qN));
    float Vd = c.coef * PI_F * 2.f * (1.f - zs) * trd;
    return Vc - Vd;
}

__global__ __launch_bounds__(1024) void solve_scalars_kernel(
        const float* a, const float* b, const float* lc, float* ws) {
    __shared__ float red[32];
    __shared__ float spec[8];
    Co c = make_co(a, b, lc);

    // bisection 1: root of integrate_dL on [0.001, 0.999]
    float lo = 0.001f, hi = 0.999f;
    for (int it = 0; it < 30; ++it) {
        float mid = 0.5f * (lo + hi);
        float d = quad_dL_blk(c, mid, red, spec);
        bool p = d < 0.f;           // fun(mid) < 0 -> hi = mid
        hi = p ? mid : hi;
        lo = p ? lo : mid;
    }
    float zs_max = 0.5f * (lo + hi);
    float L_max = quad_L_blk(c, zs_max, red, spec);

    // bisection 2: root of -integrate_V on [0.001, zs_max]
    lo = 0.001f; hi = zs_max;
    for (int it = 0; it < 30; ++it) {
        float mid = 0.5f * (lo + hi);
        float V = quad_V_blk(c, mid, red, spec);
        bool p = V > 0.f;           // (-V) < 0 -> hi = mid
        hi = p ? mid : hi;
        lo = p ? lo : mid;
    }
    float zs_crit = 0.5f * (lo + hi);
    float L_crit = quad_L_blk(c, zs_crit, red, spec);

    if (threadIdx.x == 0) {
        ws[0] = zs_max; ws[1] = L_max; ws[2] = zs_crit; ws[3] = L_crit;
    }
}

// ---------------------------------------------------------------------------
// Kernel 2: per-element Newton solve + V evaluation. One wave per element.
// ---------------------------------------------------------------------------
__global__ __launch_bounds__(256) void newton_v_kernel(
        const float* Ls, const float* a, const float* b, const float* lc,
        const float* ws, float* out, int B) {
    int gtid = blockIdx.x * blockDim.x + threadIdx.x;
    int wid = gtid >> 6;
    int lane = threadIdx.x & 63;
    if (wid >= B) return;

    Co c = make_co(a, b, lc);
    float zs_max = ws[0], L_max = ws[1], L_crit = ws[3];
    float Lq = Ls[wid];
    bool valid = Lq < L_crit;
    float L_eff = valid ? Lq : 0.5f * L_crit;
    float zs = fminf(fmaxf(L_eff / L_max * zs_max, 1e-4f), 0.9995f);

    for (int step = 0; step < 25; ++step) {
        float fs = f_of(c, zs);
        float dfs = df_of(c, zs, fs);
        float sL = 0.f, sD = 0.f;
        float l0 = 0.f, l1 = 0.f, lN = 0.f, d0 = 0.f, d1 = 0.f, dN = 0.f;
        for (int j = lane; j < MQ; j += 64) {
            float iL, iD;
            integrands_LdL(c, zs, fs, dfs, j, iL, iD);
            sL += iL; sD += iD;
            if (j == 0)            { l0 = iL; d0 = iD; }
            else if (j == 1)       { l1 = iL; d1 = iD; }
            else if (j == MQ - 1)  { lN = iL; dN = iD; }
        }
#pragma unroll
        for (int o = 32; o > 0; o >>= 1) {
            sL += __shfl_xor(sL, o, 64);
            sD += __shfl_xor(sD, o, 64);
        }
        float i0 = __shfl(l0, 0, 64), i1 = __shfl(l1, 1, 64), iN = __shfl(lN, 39, 64);
        float e0 = __shfl(d0, 0, 64), e1 = __shfl(d1, 1, 64), eN = __shfl(dN, 39, 64);
        float Lz = 4.f * zs * trapz_ext(sL, i0, i1, iN) / PI_F;
        float dL = trapz_ext(sD, e0, e1, eN) / PI_F;
        float nzs = fminf(fmaxf(zs - (Lz - L_eff) / dL, 1e-4f), 0.9995f);
        if (nzs == zs) break;   // exact fixed point: remaining iterations identical
        zs = nzs;
    }

    // V(zs): connected + disconnected pieces
    float fs = f_of(c, zs);
    float sc = 0.f, sd = 0.f;
    float c0 = 0.f, c1v = 0.f, cN = 0.f, q0 = 0.f, qN = 0.f;
    for (int j = lane; j < MQ; j += 64) {
        float vc = integrand_Vc(c, zs, fs, j);
        float vd = integrand_Vd(c, zs, j);
        sc += vc; sd += vd;
        if (j == 0)           { c0 = vc; q0 = vd; }
        else if (j == 1)      { c1v = vc; }
        else if (j == MQ - 1) { cN = vc; qN = vd; }
    }
#pragma unroll
    for (int o = 32; o > 0; o >>= 1) {
        sc += __shfl_xor(sc, o, 64);
        sd += __shfl_xor(sd, o, 64);
    }
    float i0 = __shfl(c0, 0, 64), i1 = __shfl(c1v, 1, 64), iN = __shfl(cN, 39, 64);
    float p0 = __shfl(q0, 0, 64), pN = __shfl(qN, 39, 64);
    float Vc = c.coef * PI_F * 4.f * trapz_ext(sc, i0, i1, iN) / zs;
    float trd = 0.5f * (1.f + p0) * 0.001f + 0.001f * (sd - 0.5f * (p0 + pN));
    float Vd = c.coef * PI_F * 2.f * (1.f - zs) * trd;

    if (lane == 0) out[wid] = valid ? (Vc - Vd) : 0.f;
}

// ---------------------------------------------------------------------------
extern "C" void kernel_launch(void* const* d_in, const int* in_sizes, int n_in,
                              void* d_out, int out_size, void* d_ws, size_t ws_size,
                              hipStream_t stream) {
    const float* Ls = (const float*)d_in[0];
    const float* a  = (const float*)d_in[1];
    const float* b  = (const float*)d_in[2];
    const float* lc = (const float*)d_in[3];
    float* out = (float*)d_out;
    float* ws  = (float*)d_ws;
    int B = in_sizes[0];

    solve_scalars_kernel<<<1, 1024, 0, stream>>>(a, b, lc, ws);

    int blocks = (B + 3) / 4;   // 4 waves (elements) per 256-thread block
    newton_v_kernel<<<blocks, 256, 0, stream>>>(Ls, a, b, lc, ws, out, B);
}

// Round 2
// 680.369 us; speedup vs baseline: 1.6189x; 1.6189x over previous
//
#include <hip/hip_runtime.h>
#include <math.h>

#define MQ 1000
#define PI_F 3.14159265358979323846f
#define EPSF 1e-12f
#define DYF  ((float)(0.998/999.0))   // main y-grid step
#define DY2F ((float)(0.999/999.0))   // disconnected y2-grid step

// fast HW approx ops (v_rcp_f32 / v_rsq_f32 / v_sqrt_f32, ~1 ulp)
__device__ __forceinline__ float frcp(float x)  { return __builtin_amdgcn_rcpf(x); }
__device__ __forceinline__ float frsq(float x)  { return __builtin_amdgcn_rsqf(x); }
__device__ __forceinline__ float fsqrt(float x) { return __builtin_amdgcn_sqrtf(x); }

// ---------------------------------------------------------------------------
// Coefficients (uniform). f(z) = 1 + q1 z + q2 z^2 + q3 z^3 + q4 z^4 + cf4 z^4 ln z
//   cf1=-8a0/3, cf2=-2(2a1+a0^2), cf3=-8a0a1, cf4=-4a1^2
//   q1=-cf1, q2=-cf2, q3=-cf3, q4=cf1+cf2+cf3-1
// s(z) = 1 + e1 z + e2 z^2 + e3 z^3 + e4 z^4 ;  df = 4(f - s)/z
// eval_b_ = P(z)^2, P = 1 + b0 z + b1 z^2 + p3 z^3, p3 = a0+a1-b0-b1
// g = P^2/(1-z^4);  z dg/g = 2 z P'/P + 4 z^4/(1-z^4);  sqrt(g) = P rsqrt(1-z^4)
// ---------------------------------------------------------------------------
struct Co {
    float q1, q2, q3, q4, cf4;
    float e1, e2, e3, e4;
    float b0, b1, p3;
    float coef;
};

__device__ __forceinline__ Co make_co(const float* a, const float* b, const float* lc) {
    Co c;
    float a0 = a[0], a1 = a[1];
    float cf1 = -8.f * a0 / 3.f;
    float cf2 = -2.f * (2.f * a1 + a0 * a0);
    float cf3 = -8.f * a0 * a1;
    c.cf4 = -4.f * a1 * a1;
    c.q1 = -cf1; c.q2 = -cf2; c.q3 = -cf3; c.q4 = cf1 + cf2 + cf3 - 1.f;
    c.e1 = 2.f * a0;
    c.e2 = 2.f * a1 + a0 * a0;
    c.e3 = 2.f * a0 * a1;
    c.e4 = a1 * a1;
    c.b0 = b[0]; c.b1 = b[1];
    c.p3 = a0 + a1 - b[0] - b[1];
    c.coef = expf(lc[0]);
    return c;
}

// uniform-per-zs quantities
struct Uni { float zs, fs, rfs, A4; };

__device__ __forceinline__ Uni make_uni(const Co& c, float zs) {
    Uni U; U.zs = zs;
    float z = zs, z2 = z * z, z4 = z2 * z2;
    float lg = __logf(z);
    float t4 = c.q4 + c.cf4 * lg;
    float fz = 1.f + z * (c.q1 + z * (c.q2 + z * (c.q3 + z * t4)));
    float s  = 1.f + z * (c.e1 + z * (c.e2 + z * (c.e3 + z * c.e4)));
    U.fs = fz;
    U.rfs = frcp(fz);
    float dfs = 4.f * (fz - s) * frcp(z);
    U.A4 = zs * dfs * U.rfs - 2.f;     // (zs dfs/fs + 2) - 4
    (void)z4;
    return U;
}

// L and dL integrands at one point.  y, ru4 = 1/(1-y^2)^4 precomputed.
__device__ __forceinline__ void point_LdL(const Co& c, const Uni& U,
                                          float y, float ru4,
                                          float& iL, float& iD) {
    float u  = 1.f - y * y;
    float z  = U.zs * u;
    float z2 = z * z, z4 = z2 * z2;
    float lg = __logf(z);
    float t4 = c.q4 + c.cf4 * lg;
    float fz = 1.f + z * (c.q1 + z * (c.q2 + z * (c.q3 + z * t4)));
    float s  = 1.f + z * (c.e1 + z * (c.e2 + z * (c.e3 + z * c.e4)));
    float P  = 1.f + z * (c.b0 + z * (c.b1 + z * c.p3));
    float dP = c.b0 + z * (2.f * c.b1 + z * (3.f * c.p3));
    float D  = 1.f - z4;
    float rsqD = frsq(D);
    float rcpD = rsqD * rsqD;
    float rcpP = frcp(P);
    float zdgg = 2.f * z * dP * rcpP + 4.f * z4 * rcpD;   // z dg / g
    float F4 = fz * U.rfs * ru4;                          // r4 * f/fs  (= fof/u^4)
    float S4 = s  * U.rfs * ru4;
    float den = fmaxf(F4 - 1.f, EPSF);                    // == argL == dL denominator
    float rs  = frsq(den);
    float sqg = P * rsqD;                                 // sqrt(g)
    float t1  = sqg * rs;
    iL = t1 * y;
    // t = F4*(A-4+zdgg) + 4*S4 - 2 - zdgg ; m = 2 y sqg rs^3  (sqrt(1-z/zs)=y)
    float t = F4 * (U.A4 + zdgg) + 4.f * S4 - 2.f - zdgg;
    float rs2 = rs * rs;
    iD = t * (2.f * y) * (t1 * rs2);
}

// connected-V integrand
__device__ __forceinline__ float point_Vc(const Co& c, const Uni& U,
                                          float y, float ru4) {
    float u  = 1.f - y * y;
    float z  = U.zs * u;
    float z2 = z * z, z4 = z2 * z2;
    float lg = __logf(z);
    float t4 = c.q4 + c.cf4 * lg;
    float fz = 1.f + z * (c.q1 + z * (c.q2 + z * (c.q3 + z * t4)));
    float P  = 1.f + z * (c.b0 + z * (c.b1 + z * c.p3));
    float D  = 1.f - z4;
    float rsqD = frsq(D);
    float rcpD = rsqD * rsqD;
    float fg = fz * P * P * rcpD;
    float sqfg = fsqrt(fmaxf(fg, EPSF));
    float u2 = u * u, u4 = u2 * u2;
    float rfz = frcp(fz);
    float arg = fmaxf(1.f - u4 * U.fs * rfz, EPSF);       // 1 - w^2/fof
    float t = frsq(arg) - 1.f;
    float ru2 = ru4 * u2;                                 // 1/w
    return sqfg * ru2 * t * y;
}

// disconnected-V integrand; y2 = (j+1)*dy2 grid
__device__ __forceinline__ float point_Vd(const Co& c, const Uni& U, float y2) {
    float z  = 1.f - (1.f - U.zs) * y2;
    float z2 = z * z, z4 = z2 * z2;
    float lg = __logf(z);
    float t4 = c.q4 + c.cf4 * lg;
    float fz = 1.f + z * (c.q1 + z * (c.q2 + z * (c.q3 + z * t4)));
    float P  = 1.f + z * (c.b0 + z * (c.b1 + z * c.p3));
    float D  = 1.f - z4;
    float rsqD = frsq(D);
    float fg = fz * P * P * (rsqD * rsqD);
    float sq = fsqrt(fmaxf(fg, EPSF));
    float rz = frcp(z);
    return sq * rz * rz;
}

// trapz over extended grid yy=[0, y..., 1], ii=[v0, integ..., 0]
__device__ __forceinline__ float trapz_ext(float S, float i0, float i1, float iN) {
    float slope = (i1 - i0) * frcp(DYF);
    float v0 = i0 - slope * 0.001f;
    float yLast = 0.001f + 999.f * DYF;
    return DYF * (S - 0.5f * (i0 + iN))
         + 0.5f * (v0 + i0) * 0.001f
         + 0.5f * iN * (1.f - yLast);
}

__device__ __forceinline__ float trapz_d(float S, float q0, float qN) {
    return 0.5f * (1.f + q0) * 0.001f + DY2F * (S - 0.5f * (q0 + qN));
}

// ---------------------------------------------------------------------------
// Kernel 1: scalar bisections.  One 1024-thread block, one point per thread.
// ---------------------------------------------------------------------------
__device__ __forceinline__ void block_red2(float v1, float v2, float* red,
                                           float& s1, float& s2) {
    int lane = threadIdx.x & 63;
    int w = threadIdx.x >> 6;
#pragma unroll
    for (int o = 32; o > 0; o >>= 1) {
        v1 += __shfl_xor(v1, o, 64);
        v2 += __shfl_xor(v2, o, 64);
    }
    if (lane == 0) { red[w] = v1; red[16 + w] = v2; }
    __syncthreads();
    if (threadIdx.x < 64) {
        float t1 = (lane < 16) ? red[lane] : 0.f;
        float t2 = (lane < 16) ? red[16 + lane] : 0.f;
#pragma unroll
        for (int o = 8; o > 0; o >>= 1) {
            t1 += __shfl_xor(t1, o, 64);
            t2 += __shfl_xor(t2, o, 64);
        }
        if (lane == 0) { red[0] = t1; red[16] = t2; }
    }
    __syncthreads();
    s1 = red[0]; s2 = red[16];
    __syncthreads();   // epoch boundary before red/spec reuse
}

__global__ __launch_bounds__(1024) void solve_scalars_kernel(
        const float* a, const float* b, const float* lc, float* ws) {
    __shared__ float red[32];
    __shared__ float spec[8];
    Co c = make_co(a, b, lc);

    int j = threadIdx.x;
    bool act = (j < MQ);
    float y = fmaf((float)j, DYF, 0.001f);
    float u = 1.f - y * y;
    float u2 = u * u;
    float ru4 = frcp(u2 * u2);
    float y2 = fmaf((float)j, DY2F, 0.001f);

    // --- bisection 1: root of dL on [0.001, 0.999] ---
    float lo = 0.001f, hi = 0.999f, zs_max, L_max;
    for (int it = 0; it <= 30; ++it) {
        float mid = (it < 30) ? 0.5f * (lo + hi) : 0.5f * (lo + hi);
        Uni U = make_uni(c, mid);
        float iL = 0.f, iD = 0.f;
        if (act) point_LdL(c, U, y, ru4, iL, iD);
        if (j == 0)      { spec[0] = iL; spec[3] = iD; }
        if (j == 1)      { spec[1] = iL; spec[4] = iD; }
        if (j == MQ - 1) { spec[2] = iL; spec[5] = iD; }
        __syncthreads();
        float a0 = spec[0], a1v = spec[1], aN = spec[2];
        float b0 = spec[3], b1v = spec[4], bN = spec[5];
        float SL, SD;
        block_red2(iL, iD, red, SL, SD);
        if (it == 30) {   // final: evaluate L at zs_max
            L_max = 4.f * mid * trapz_ext(SL, a0, a1v, aN) / PI_F;
            zs_max = mid;
            break;
        }
        float dL = trapz_ext(SD, b0, b1v, bN) / PI_F;
        bool p = dL < 0.f;
        hi = p ? mid : hi;
        lo = p ? lo : mid;
    }

    // --- bisection 2: root of -V on [0.001, zs_max] ---
    lo = 0.001f; hi = zs_max;
    float zs_crit, L_crit;
    for (int it = 0; it < 30; ++it) {
        float mid = 0.5f * (lo + hi);
        Uni U = make_uni(c, mid);
        float vc = 0.f, vd = 0.f;
        if (act) { vc = point_Vc(c, U, y, ru4); vd = point_Vd(c, U, y2); }
        if (j == 0)      { spec[0] = vc; spec[3] = vd; }
        if (j == 1)      { spec[1] = vc; }
        if (j == MQ - 1) { spec[2] = vc; spec[4] = vd; }
        __syncthreads();
        float a0 = spec[0], a1v = spec[1], aN = spec[2];
        float p0 = spec[3], pN = spec[4];
        float Sc, Sd;
        block_red2(vc, vd, red, Sc, Sd);
        float Vc = c.coef * PI_F * 4.f * trapz_ext(Sc, a0, a1v, aN) * frcp(mid);
        float Vd = c.coef * PI_F * 2.f * (1.f - mid) * trapz_d(Sd, p0, pN);
        float V = Vc - Vd;
        bool p = V > 0.f;   // (-V) < 0 -> hi = mid
        hi = p ? mid : hi;
        lo = p ? lo : mid;
    }
    zs_crit = 0.5f * (lo + hi);
    {
        Uni U = make_uni(c, zs_crit);
        float iL = 0.f, iD = 0.f;
        if (act) point_LdL(c, U, y, ru4, iL, iD);
        if (j == 0)      { spec[0] = iL; }
        if (j == 1)      { spec[1] = iL; }
        if (j == MQ - 1) { spec[2] = iL; }
        __syncthreads();
        float a0 = spec[0], a1v = spec[1], aN = spec[2];
        float SL, SD;
        block_red2(iL, iD, red, SL, SD);
        L_crit = 4.f * zs_crit * trapz_ext(SL, a0, a1v, aN) / PI_F;
    }

    if (threadIdx.x == 0) {
        ws[0] = zs_max; ws[1] = L_max; ws[2] = zs_crit; ws[3] = L_crit;
    }
}

// ---------------------------------------------------------------------------
// Kernel 2: per-element Newton + V.  One wave per element, 16 points/lane.
// j = lane + 64k; j==0,1 -> k=0 lanes 0,1;  j==999 -> k=15 lane 39.
// ---------------------------------------------------------------------------
__global__ __launch_bounds__(256, 4) void newton_v_kernel(
        const float* Ls, const float* a, const float* b, const float* lc,
        const float* ws, float* out, int B) {
    int wid = (blockIdx.x * blockDim.x + threadIdx.x) >> 6;
    int lane = threadIdx.x & 63;
    if (wid >= B) return;

    Co c = make_co(a, b, lc);

    // loop-invariant per-point grid values
    float y_[16], ru4_[16];
#pragma unroll
    for (int k = 0; k < 16; ++k) {
        int j = lane + 64 * k;
        float y = fmaf((float)j, DYF, 0.001f);
        y_[k] = y;
        float u = 1.f - y * y;
        float u2 = u * u;
        ru4_[k] = frcp(u2 * u2);
    }

    float zs_max = ws[0], L_max = ws[1], L_crit = ws[3];
    float Lq = Ls[wid];
    bool valid = Lq < L_crit;
    float L_eff = valid ? Lq : 0.5f * L_crit;
    float zs = fminf(fmaxf(L_eff * frcp(L_max) * zs_max, 1e-4f), 0.9995f);
    float zs_prev = -1.f;

    for (int step = 0; step < 25; ++step) {
        Uni U = make_uni(c, zs);
        float sL = 0.f, sD = 0.f, l0 = 0.f, d0 = 0.f, lN = 0.f, dN = 0.f;
#pragma unroll
        for (int k = 0; k < 16; ++k) {
            if (k == 15 && lane >= 40) break;
            float iL, iD;
            point_LdL(c, U, y_[k], ru4_[k], iL, iD);
            sL += iL; sD += iD;
            if (k == 0)  { l0 = iL; d0 = iD; }
            if (k == 15) { lN = iL; dN = iD; }
        }
#pragma unroll
        for (int o = 32; o > 0; o >>= 1) {
            sL += __shfl_xor(sL, o, 64);
            sD += __shfl_xor(sD, o, 64);
        }
        float i0 = __shfl(l0, 0, 64), i1 = __shfl(l0, 1, 64), iN = __shfl(lN, 39, 64);
        float e0 = __shfl(d0, 0, 64), e1 = __shfl(d0, 1, 64), eN = __shfl(dN, 39, 64);
        float Lz = 4.f * zs * trapz_ext(sL, i0, i1, iN) / PI_F;
        float dL = trapz_ext(sD, e0, e1, eN) / PI_F;
        float nzs = fminf(fmaxf(zs - (Lz - L_eff) * frcp(dL), 1e-4f), 0.9995f);
        if (nzs == zs || nzs == zs_prev) break;   // fixed point or 2-cycle
        zs_prev = zs;
        zs = nzs;
    }

    // V(zs)
    Uni U = make_uni(c, zs);
    float sc = 0.f, sd = 0.f, c0 = 0.f, cN = 0.f, q0 = 0.f, qN = 0.f;
#pragma unroll
    for (int k = 0; k < 16; ++k) {
        if (k == 15 && lane >= 40) break;
        int j = lane + 64 * k;
        float vc = point_Vc(c, U, y_[k], ru4_[k]);
        float y2 = fmaf((float)j, DY2F, 0.001f);
        float vd = point_Vd(c, U, y2);
        sc += vc; sd += vd;
        if (k == 0)  { c0 = vc; q0 = vd; }
        if (k == 15) { cN = vc; qN = vd; }
    }
#pragma unroll
    for (int o = 32; o > 0; o >>= 1) {
        sc += __shfl_xor(sc, o, 64);
        sd += __shfl_xor(sd, o, 64);
    }
    float i0 = __shfl(c0, 0, 64), i1 = __shfl(c0, 1, 64), iN = __shfl(cN, 39, 64);
    float p0 = __shfl(q0, 0, 64), pN = __shfl(qN, 39, 64);
    float Vc = c.coef * PI_F * 4.f * trapz_ext(sc, i0, i1, iN) * frcp(zs);
    float Vd = c.coef * PI_F * 2.f * (1.f - zs) * trapz_d(sd, p0, pN);

    if (lane == 0) out[wid] = valid ? (Vc - Vd) : 0.f;
}

// ---------------------------------------------------------------------------
extern "C" void kernel_launch(void* const* d_in, const int* in_sizes, int n_in,
                              void* d_out, int out_size, void* d_ws, size_t ws_size,
                              hipStream_t stream) {
    const float* Ls = (const float*)d_in[0];
    const float* a  = (const float*)d_in[1];
    const float* b  = (const float*)d_in[2];
    const float* lc = (const float*)d_in[3];
    float* out = (float*)d_out;
    float* ws  = (float*)d_ws;
    int B = in_sizes[0];

    solve_scalars_kernel<<<1, 1024, 0, stream>>>(a, b, lc, ws);

    int blocks = (B + 3) / 4;   // 4 waves (elements) per 256-thread block
    newton_v_kernel<<<blocks, 256, 0, stream>>>(Ls, a, b, lc, ws, out, B);
}

// Round 3
// 660.437 us; speedup vs baseline: 1.6678x; 1.0302x over previous
//
#include <hip/hip_runtime.h>
#include <math.h>

#define MQ 1000
#define PI_F 3.14159265358979323846f
#define EPSF 1e-12f
#define DYF  ((float)(0.998/999.0))   // main y-grid step
#define DY2F ((float)(0.999/999.0))   // disconnected y2-grid step

// fast HW approx ops (v_rcp_f32 / v_rsq_f32 / v_sqrt_f32, ~1 ulp)
__device__ __forceinline__ float frcp(float x)  { return __builtin_amdgcn_rcpf(x); }
__device__ __forceinline__ float frsq(float x)  { return __builtin_amdgcn_rsqf(x); }
__device__ __forceinline__ float fsqrt(float x) { return __builtin_amdgcn_sqrtf(x); }

// ---------------------------------------------------------------------------
// f(z) = 1 + q1 z + q2 z^2 + q3 z^3 + (q4 + cf4 ln z) z^4
// s(z) = 1 + e1 z + e2 z^2 + e3 z^3 + e4 z^4 ;  df = 4(f - s)/z
// eval_b_ = P(z)^2, P = 1 + b0 z + b1 z^2 + p3 z^3, p3 = a0+a1-b0-b1
// g = P^2/(1-z^4);  z dg/g = 2 z P'/P + 4 z^4/(1-z^4);  sqrt(g) = P rsqrt(1-z^4)
// ---------------------------------------------------------------------------
struct Co {
    float q1, q2, q3, q4, cf4;
    float e1, e2, e3, e4;
    float b0, b1, p3;
    float coef;
};

__device__ __forceinline__ Co make_co(const float* a, const float* b, const float* lc) {
    Co c;
    float a0 = a[0], a1 = a[1];
    float cf1 = -8.f * a0 / 3.f;
    float cf2 = -2.f * (2.f * a1 + a0 * a0);
    float cf3 = -8.f * a0 * a1;
    c.cf4 = -4.f * a1 * a1;
    c.q1 = -cf1; c.q2 = -cf2; c.q3 = -cf3; c.q4 = cf1 + cf2 + cf3 - 1.f;
    c.e1 = 2.f * a0;
    c.e2 = 2.f * a1 + a0 * a0;
    c.e3 = 2.f * a0 * a1;
    c.e4 = a1 * a1;
    c.b0 = b[0]; c.b1 = b[1];
    c.p3 = a0 + a1 - b[0] - b[1];
    c.coef = expf(lc[0]);
    return c;
}

struct Uni { float zs, fs, rfs, A4; };

__device__ __forceinline__ Uni make_uni(const Co& c, float zs) {
    Uni U; U.zs = zs;
    float z = zs;
    float lg = __logf(z);
    float t4 = c.q4 + c.cf4 * lg;
    float fz = 1.f + z * (c.q1 + z * (c.q2 + z * (c.q3 + z * t4)));
    float s  = 1.f + z * (c.e1 + z * (c.e2 + z * (c.e3 + z * c.e4)));
    U.fs = fz;
    U.rfs = frcp(fz);
    float dfs = 4.f * (fz - s) * frcp(z);
    U.A4 = zs * dfs * U.rfs - 2.f;     // (zs dfs/fs + 2) - 4
    return U;
}

// L and dL integrands at one point; y and u = 1-y^2 passed in.
__device__ __forceinline__ void point_LdL(const Co& c, const Uni& U,
                                          float y, float u,
                                          float& iL, float& iD) {
    float u2  = u * u;
    float ru2 = frcp(u2);
    float ru4 = ru2 * ru2;
    float z  = U.zs * u;
    float z2 = z * z, z4 = z2 * z2;
    float lg = __logf(z);
    float t4 = c.q4 + c.cf4 * lg;
    float fz = 1.f + z * (c.q1 + z * (c.q2 + z * (c.q3 + z * t4)));
    float s  = 1.f + z * (c.e1 + z * (c.e2 + z * (c.e3 + z * c.e4)));
    float P  = 1.f + z * (c.b0 + z * (c.b1 + z * c.p3));
    float dP = c.b0 + z * (2.f * c.b1 + z * (3.f * c.p3));
    float D  = 1.f - z4;
    float rsqD = frsq(D);
    float rcpD = rsqD * rsqD;
    float rcpP = frcp(P);
    float zdgg = 2.f * z * dP * rcpP + 4.f * z4 * rcpD;   // z dg / g
    float F4 = fz * U.rfs * ru4;                          // r4 * f/fs
    float S4 = s  * U.rfs * ru4;
    float den = fmaxf(F4 - 1.f, EPSF);                    // argL == dL denominator
    float rs  = frsq(den);
    float sqg = P * rsqD;                                 // sqrt(g)
    float t1  = sqg * rs;
    iL = t1 * y;
    float t = F4 * (U.A4 + zdgg) + 4.f * S4 - 2.f - zdgg;
    float rs2 = rs * rs;
    iD = t * (2.f * y) * (t1 * rs2);                      // sqrt(1-z/zs) = y
}

// connected-V integrand
__device__ __forceinline__ float point_Vc(const Co& c, const Uni& U,
                                          float y, float u) {
    float u2  = u * u;
    float u4  = u2 * u2;
    float ru2 = frcp(u2);                                 // 1/w
    float z  = U.zs * u;
    float z2 = z * z, z4 = z2 * z2;
    float lg = __logf(z);
    float t4 = c.q4 + c.cf4 * lg;
    float fz = 1.f + z * (c.q1 + z * (c.q2 + z * (c.q3 + z * t4)));
    float P  = 1.f + z * (c.b0 + z * (c.b1 + z * c.p3));
    float D  = 1.f - z4;
    float rsqD = frsq(D);
    float rcpD = rsqD * rsqD;
    float fg = fz * P * P * rcpD;
    float sqfg = fsqrt(fmaxf(fg, EPSF));
    float rfz = frcp(fz);
    float arg = fmaxf(1.f - u4 * U.fs * rfz, EPSF);       // 1 - w^2/fof
    float t = frsq(arg) - 1.f;
    return sqfg * ru2 * t * y;
}

// disconnected-V integrand on the y2 grid
__device__ __forceinline__ float point_Vd(const Co& c, const Uni& U, float y2) {
    float z  = 1.f - (1.f - U.zs) * y2;
    float z2 = z * z, z4 = z2 * z2;
    float lg = __logf(z);
    float t4 = c.q4 + c.cf4 * lg;
    float fz = 1.f + z * (c.q1 + z * (c.q2 + z * (c.q3 + z * t4)));
    float P  = 1.f + z * (c.b0 + z * (c.b1 + z * c.p3));
    float D  = 1.f - z4;
    float rsqD = frsq(D);
    float fg = fz * P * P * (rsqD * rsqD);
    float sq = fsqrt(fmaxf(fg, EPSF));
    float rz = frcp(z);
    return sq * rz * rz;
}

// trapz over extended grid yy=[0, y..., 1], ii=[v0, integ..., 0]
__device__ __forceinline__ float trapz_ext(float S, float i0, float i1, float iN) {
    float slope = (i1 - i0) * frcp(DYF);
    float v0 = i0 - slope * 0.001f;
    float yLast = 0.001f + 999.f * DYF;
    return DYF * (S - 0.5f * (i0 + iN))
         + 0.5f * (v0 + i0) * 0.001f
         + 0.5f * iN * (1.f - yLast);
}

__device__ __forceinline__ float trapz_d(float S, float q0, float qN) {
    return 0.5f * (1.f + q0) * 0.001f + DY2F * (S - 0.5f * (q0 + qN));
}

// ---------------------------------------------------------------------------
// Kernel 1: scalar bisections.  256 threads = 4 waves, 4 points/thread,
// 2 barriers per quadrature.  j = t + 256k; j==0,1 -> t=0,1; j==999 -> t=231.
// ---------------------------------------------------------------------------
__global__ __launch_bounds__(256) void solve_scalars_kernel(
        const float* a, const float* b, const float* lc, float* ws) {
    __shared__ float pA[4], pB[4], spec[6];
    Co c = make_co(a, b, lc);
    int t = threadIdx.x;
    int lane = t & 63, w = t >> 6;

    float zs_max = 0.f, L_max = 0.f;

    // --- bisection 1 (root of dL) + final L_max eval at it==30 ---
    float lo = 0.001f, hi = 0.999f;
    for (int it = 0; it <= 30; ++it) {
        float mid = 0.5f * (lo + hi);
        Uni U = make_uni(c, mid);
        float sL = 0.f, sD = 0.f;
        float l0 = 0.f, l1 = 0.f, lN = 0.f, d0 = 0.f, d1 = 0.f, dN = 0.f;
#pragma unroll
        for (int k = 0; k < 4; ++k) {
            int j = t + 256 * k;
            if (k < 3 || t < 232) {
                float y = fmaf((float)j, DYF, 0.001f);
                float u = 1.f - y * y;
                float iL, iD;
                point_LdL(c, U, y, u, iL, iD);
                sL += iL; sD += iD;
                if (k == 0) {
                    if (t == 0) { l0 = iL; d0 = iD; }
                    if (t == 1) { l1 = iL; d1 = iD; }
                }
                if (k == 3 && t == 231) { lN = iL; dN = iD; }
            }
        }
#pragma unroll
        for (int o = 32; o > 0; o >>= 1) {
            sL += __shfl_xor(sL, o, 64);
            sD += __shfl_xor(sD, o, 64);
        }
        if (lane == 0) { pA[w] = sL; pB[w] = sD; }
        if (t == 0)   { spec[0] = l0; spec[3] = d0; }
        if (t == 1)   { spec[1] = l1; spec[4] = d1; }
        if (t == 231) { spec[2] = lN; spec[5] = dN; }
        __syncthreads();
        float SL = pA[0] + pA[1] + pA[2] + pA[3];
        float SD = pB[0] + pB[1] + pB[2] + pB[3];
        float i0 = spec[0], i1 = spec[1], iN = spec[2];
        float e0 = spec[3], e1 = spec[4], eN = spec[5];
        __syncthreads();   // epoch end: LDS reusable next iter
        if (it == 30) {
            zs_max = mid;
            L_max = 4.f * mid * trapz_ext(SL, i0, i1, iN) / PI_F;
            break;
        }
        float dL = trapz_ext(SD, e0, e1, eN) / PI_F;
        bool p = dL < 0.f;                 // fun(mid) < 0 -> hi = mid
        hi = p ? mid : hi;
        lo = p ? lo : mid;
    }

    // --- bisection 2 (root of -V) on [0.001, zs_max] ---
    lo = 0.001f; hi = zs_max;
    for (int it = 0; it < 30; ++it) {
        float mid = 0.5f * (lo + hi);
        Uni U = make_uni(c, mid);
        float sc = 0.f, sd = 0.f;
        float c0 = 0.f, c1v = 0.f, cN = 0.f, q0 = 0.f, qN = 0.f;
#pragma unroll
        for (int k = 0; k < 4; ++k) {
            int j = t + 256 * k;
            if (k < 3 || t < 232) {
                float y = fmaf((float)j, DYF, 0.001f);
                float u = 1.f - y * y;
                float vc = point_Vc(c, U, y, u);
                float y2 = fmaf((float)j, DY2F, 0.001f);
                float vd = point_Vd(c, U, y2);
                sc += vc; sd += vd;
                if (k == 0) {
                    if (t == 0) { c0 = vc; q0 = vd; }
                    if (t == 1) { c1v = vc; }
                }
                if (k == 3 && t == 231) { cN = vc; qN = vd; }
            }
        }
#pragma unroll
        for (int o = 32; o > 0; o >>= 1) {
            sc += __shfl_xor(sc, o, 64);
            sd += __shfl_xor(sd, o, 64);
        }
        if (lane == 0) { pA[w] = sc; pB[w] = sd; }
        if (t == 0)   { spec[0] = c0; spec[3] = q0; }
        if (t == 1)   { spec[1] = c1v; }
        if (t == 231) { spec[2] = cN; spec[4] = qN; }
        __syncthreads();
        float Sc = pA[0] + pA[1] + pA[2] + pA[3];
        float Sd = pB[0] + pB[1] + pB[2] + pB[3];
        float i0 = spec[0], i1 = spec[1], iN = spec[2];
        float p0 = spec[3], pN = spec[4];
        __syncthreads();
        float Vc = c.coef * PI_F * 4.f * trapz_ext(Sc, i0, i1, iN) * frcp(mid);
        float Vd = c.coef * PI_F * 2.f * (1.f - mid) * trapz_d(Sd, p0, pN);
        bool p = (Vc - Vd) > 0.f;          // (-V) < 0 -> hi = mid
        hi = p ? mid : hi;
        lo = p ? lo : mid;
    }
    float zs_crit = 0.5f * (lo + hi);

    // --- L at zs_crit ---
    float L_crit;
    {
        Uni U = make_uni(c, zs_crit);
        float sL = 0.f, sD = 0.f;
        float l0 = 0.f, l1 = 0.f, lN = 0.f;
#pragma unroll
        for (int k = 0; k < 4; ++k) {
            int j = t + 256 * k;
            if (k < 3 || t < 232) {
                float y = fmaf((float)j, DYF, 0.001f);
                float u = 1.f - y * y;
                float iL, iD;
                point_LdL(c, U, y, u, iL, iD);
                sL += iL; sD += iD;
                if (k == 0) {
                    if (t == 0) l0 = iL;
                    if (t == 1) l1 = iL;
                }
                if (k == 3 && t == 231) lN = iL;
            }
        }
#pragma unroll
        for (int o = 32; o > 0; o >>= 1) sL += __shfl_xor(sL, o, 64);
        if (lane == 0) pA[w] = sL;
        if (t == 0)   spec[0] = l0;
        if (t == 1)   spec[1] = l1;
        if (t == 231) spec[2] = lN;
        __syncthreads();
        float SL = pA[0] + pA[1] + pA[2] + pA[3];
        L_crit = 4.f * zs_crit * trapz_ext(SL, spec[0], spec[1], spec[2]) / PI_F;
    }

    if (t == 0) {
        ws[0] = zs_max; ws[1] = L_max; ws[2] = zs_crit; ws[3] = L_crit;
    }
}

// ---------------------------------------------------------------------------
// Kernel 2: per-element Newton + V.  One wave per element, 16 points/lane,
// everything recomputed in-register (NO per-lane arrays -> no scratch).
// j = lane + 64k; j==0,1 -> k=0 lanes 0,1;  j==999 -> k=15 lane 39.
// ---------------------------------------------------------------------------
__global__ __launch_bounds__(256, 4) void newton_v_kernel(
        const float* Ls, const float* a, const float* b, const float* lc,
        const float* ws, float* out, int B) {
    int wid = (blockIdx.x * blockDim.x + threadIdx.x) >> 6;
    int lane = threadIdx.x & 63;
    if (wid >= B) return;

    Co c = make_co(a, b, lc);
    float zs_max = ws[0], L_max = ws[1], L_crit = ws[3];
    float Lq = Ls[wid];
    bool valid = Lq < L_crit;
    float L_eff = valid ? Lq : 0.5f * L_crit;
    float zs = fminf(fmaxf(L_eff * frcp(L_max) * zs_max, 1e-4f), 0.9995f);
    float zs_prev = -1.f;

    for (int step = 0; step < 25; ++step) {
        Uni U = make_uni(c, zs);
        float sL = 0.f, sD = 0.f, l0 = 0.f, d0 = 0.f, lN = 0.f, dN = 0.f;
#pragma unroll
        for (int k = 0; k < 16; ++k) {
            if (k < 15 || lane < 40) {     // j < 1000; constant-true for k<15
                int j = lane + 64 * k;
                float y = fmaf((float)j, DYF, 0.001f);
                float u = 1.f - y * y;
                float iL, iD;
                point_LdL(c, U, y, u, iL, iD);
                sL += iL; sD += iD;
                if (k == 0)  { l0 = iL; d0 = iD; }
                if (k == 15) { lN = iL; dN = iD; }
            }
        }
#pragma unroll
        for (int o = 32; o > 0; o >>= 1) {
            sL += __shfl_xor(sL, o, 64);
            sD += __shfl_xor(sD, o, 64);
        }
        float i0 = __shfl(l0, 0, 64), i1 = __shfl(l0, 1, 64), iN = __shfl(lN, 39, 64);
        float e0 = __shfl(d0, 0, 64), e1 = __shfl(d0, 1, 64), eN = __shfl(dN, 39, 64);
        float Lz = 4.f * zs * trapz_ext(sL, i0, i1, iN) / PI_F;
        float dL = trapz_ext(sD, e0, e1, eN) / PI_F;
        float nzs = fminf(fmaxf(zs - (Lz - L_eff) * frcp(dL), 1e-4f), 0.9995f);
        if (nzs == zs || nzs == zs_prev) break;   // fixed point or 2-cycle
        zs_prev = zs;
        zs = nzs;
    }

    // V(zs)
    Uni U = make_uni(c, zs);
    float sc = 0.f, sd = 0.f, c0 = 0.f, cN = 0.f, q0 = 0.f, qN = 0.f;
#pragma unroll
    for (int k = 0; k < 16; ++k) {
        if (k < 15 || lane < 40) {
            int j = lane + 64 * k;
            float y = fmaf((float)j, DYF, 0.001f);
            float u = 1.f - y * y;
            float vc = point_Vc(c, U, y, u);
            float y2 = fmaf((float)j, DY2F, 0.001f);
            float vd = point_Vd(c, U, y2);
            sc += vc; sd += vd;
            if (k == 0)  { c0 = vc; q0 = vd; }
            if (k == 15) { cN = vc; qN = vd; }
        }
    }
#pragma unroll
    for (int o = 32; o > 0; o >>= 1) {
        sc += __shfl_xor(sc, o, 64);
        sd += __shfl_xor(sd, o, 64);
    }
    float i0 = __shfl(c0, 0, 64), i1 = __shfl(c0, 1, 64), iN = __shfl(cN, 39, 64);
    float p0 = __shfl(q0, 0, 64), pN = __shfl(qN, 39, 64);
    float Vc = c.coef * PI_F * 4.f * trapz_ext(sc, i0, i1, iN) * frcp(zs);
    float Vd = c.coef * PI_F * 2.f * (1.f - zs) * trapz_d(sd, p0, pN);

    if (lane == 0) out[wid] = valid ? (Vc - Vd) : 0.f;
}

// ---------------------------------------------------------------------------
extern "C" void kernel_launch(void* const* d_in, const int* in_sizes, int n_in,
                              void* d_out, int out_size, void* d_ws, size_t ws_size,
                              hipStream_t stream) {
    const float* Ls = (const float*)d_in[0];
    const float* a  = (const float*)d_in[1];
    const float* b  = (const float*)d_in[2];
    const float* lc = (const float*)d_in[3];
    float* out = (float*)d_out;
    float* ws  = (float*)d_ws;
    int B = in_sizes[0];

    solve_scalars_kernel<<<1, 256, 0, stream>>>(a, b, lc, ws);

    int blocks = (B + 3) / 4;   // 4 waves (elements) per 256-thread block
    newton_v_kernel<<<blocks, 256, 0, stream>>>(Ls, a, b, lc, ws, out, B);
}

// Round 4
// 318.684 us; speedup vs baseline: 3.4563x; 2.0724x over previous
//
#include <hip/hip_runtime.h>
#include <math.h>

#define MQ 1000
#define PI_F 3.14159265358979323846f
#define EPSF 1e-12f
#define DYF  ((float)(0.998/999.0))   // main y-grid step
#define DY2F ((float)(0.999/999.0))   // disconnected y2-grid step

// fast HW approx ops (v_rcp_f32 / v_rsq_f32 / v_sqrt_f32, ~1 ulp)
__device__ __forceinline__ float frcp(float x)  { return __builtin_amdgcn_rcpf(x); }
__device__ __forceinline__ float frsq(float x)  { return __builtin_amdgcn_rsqf(x); }
__device__ __forceinline__ float fsqrt(float x) { return __builtin_amdgcn_sqrtf(x); }

// ---------------------------------------------------------------------------
// f(z) = 1 + q1 z + q2 z^2 + q3 z^3 + (q4 + cf4 ln z) z^4
// s(z) = 1 + e1 z + e2 z^2 + e3 z^3 + e4 z^4 ;  df = 4(f - s)/z
// eval_b_ = P(z)^2, P = 1 + b0 z + b1 z^2 + p3 z^3, p3 = a0+a1-b0-b1
// g = P^2/(1-z^4);  z dg/g = 2 z P'/P + 4 z^4/(1-z^4);  sqrt(g) = P rsqrt(1-z^4)
// ---------------------------------------------------------------------------
struct Co {
    float q1, q2, q3, q4, cf4;
    float e1, e2, e3, e4;
    float b0, b1, p3;
    float coef;
};

__device__ __forceinline__ Co make_co(const float* a, const float* b, const float* lc) {
    Co c;
    float a0 = a[0], a1 = a[1];
    float cf1 = -8.f * a0 / 3.f;
    float cf2 = -2.f * (2.f * a1 + a0 * a0);
    float cf3 = -8.f * a0 * a1;
    c.cf4 = -4.f * a1 * a1;
    c.q1 = -cf1; c.q2 = -cf2; c.q3 = -cf3; c.q4 = cf1 + cf2 + cf3 - 1.f;
    c.e1 = 2.f * a0;
    c.e2 = 2.f * a1 + a0 * a0;
    c.e3 = 2.f * a0 * a1;
    c.e4 = a1 * a1;
    c.b0 = b[0]; c.b1 = b[1];
    c.p3 = a0 + a1 - b[0] - b[1];
    c.coef = expf(lc[0]);
    return c;
}

struct Uni { float zs, fs, rfs, A4; };

__device__ __forceinline__ Uni make_uni(const Co& c, float zs) {
    Uni U; U.zs = zs;
    float z = zs;
    float lg = __logf(z);
    float t4 = c.q4 + c.cf4 * lg;
    float fz = 1.f + z * (c.q1 + z * (c.q2 + z * (c.q3 + z * t4)));
    float s  = 1.f + z * (c.e1 + z * (c.e2 + z * (c.e3 + z * c.e4)));
    U.fs = fz;
    U.rfs = frcp(fz);
    float dfs = 4.f * (fz - s) * frcp(z);
    U.A4 = zs * dfs * U.rfs - 2.f;     // (zs dfs/fs + 2) - 4
    return U;
}

// L and dL integrands at one point; y and u = 1-y^2 passed in.
__device__ __forceinline__ void point_LdL(const Co& c, const Uni& U,
                                          float y, float u,
                                          float& iL, float& iD) {
    float u2  = u * u;
    float ru2 = frcp(u2);
    float ru4 = ru2 * ru2;
    float z  = U.zs * u;
    float z2 = z * z, z4 = z2 * z2;
    float lg = __logf(z);
    float t4 = c.q4 + c.cf4 * lg;
    float fz = 1.f + z * (c.q1 + z * (c.q2 + z * (c.q3 + z * t4)));
    float s  = 1.f + z * (c.e1 + z * (c.e2 + z * (c.e3 + z * c.e4)));
    float P  = 1.f + z * (c.b0 + z * (c.b1 + z * c.p3));
    float dP = c.b0 + z * (2.f * c.b1 + z * (3.f * c.p3));
    float D  = 1.f - z4;
    float rsqD = frsq(D);
    float rcpD = rsqD * rsqD;
    float rcpP = frcp(P);
    float zdgg = 2.f * z * dP * rcpP + 4.f * z4 * rcpD;   // z dg / g
    float F4 = fz * U.rfs * ru4;                          // r4 * f/fs
    float S4 = s  * U.rfs * ru4;
    float den = fmaxf(F4 - 1.f, EPSF);                    // argL == dL denominator
    float rs  = frsq(den);
    float sqg = P * rsqD;                                 // sqrt(g)
    float t1  = sqg * rs;
    iL = t1 * y;
    float t = F4 * (U.A4 + zdgg) + 4.f * S4 - 2.f - zdgg;
    float rs2 = rs * rs;
    iD = t * (2.f * y) * (t1 * rs2);                      // sqrt(1-z/zs) = y
}

// connected-V integrand
__device__ __forceinline__ float point_Vc(const Co& c, const Uni& U,
                                          float y, float u) {
    float u2  = u * u;
    float u4  = u2 * u2;
    float ru2 = frcp(u2);                                 // 1/w
    float z  = U.zs * u;
    float z2 = z * z, z4 = z2 * z2;
    float lg = __logf(z);
    float t4 = c.q4 + c.cf4 * lg;
    float fz = 1.f + z * (c.q1 + z * (c.q2 + z * (c.q3 + z * t4)));
    float P  = 1.f + z * (c.b0 + z * (c.b1 + z * c.p3));
    float D  = 1.f - z4;
    float rsqD = frsq(D);
    float rcpD = rsqD * rsqD;
    float fg = fz * P * P * rcpD;
    float sqfg = fsqrt(fmaxf(fg, EPSF));
    float rfz = frcp(fz);
    float arg = fmaxf(1.f - u4 * U.fs * rfz, EPSF);       // 1 - w^2/fof
    float t = frsq(arg) - 1.f;
    return sqfg * ru2 * t * y;
}

// disconnected-V integrand on the y2 grid
__device__ __forceinline__ float point_Vd(const Co& c, const Uni& U, float y2) {
    float z  = 1.f - (1.f - U.zs) * y2;
    float z2 = z * z, z4 = z2 * z2;
    float lg = __logf(z);
    float t4 = c.q4 + c.cf4 * lg;
    float fz = 1.f + z * (c.q1 + z * (c.q2 + z * (c.q3 + z * t4)));
    float P  = 1.f + z * (c.b0 + z * (c.b1 + z * c.p3));
    float D  = 1.f - z4;
    float rsqD = frsq(D);
    float fg = fz * P * P * (rsqD * rsqD);
    float sq = fsqrt(fmaxf(fg, EPSF));
    float rz = frcp(z);
    return sq * rz * rz;
}

// trapz over extended grid yy=[0, y..., 1], ii=[v0, integ..., 0]
__device__ __forceinline__ float trapz_ext(float S, float i0, float i1, float iN) {
    float slope = (i1 - i0) * frcp(DYF);
    float v0 = i0 - slope * 0.001f;
    float yLast = 0.001f + 999.f * DYF;
    return DYF * (S - 0.5f * (i0 + iN))
         + 0.5f * (v0 + i0) * 0.001f
         + 0.5f * iN * (1.f - yLast);
}

__device__ __forceinline__ float trapz_d(float S, float q0, float qN) {
    return 0.5f * (1.f + q0) * 0.001f + DY2F * (S - 0.5f * (q0 + qN));
}

// ---------------------------------------------------------------------------
// Kernel 1: scalar bisections.  256 threads = 4 waves, 4 points/thread,
// 2 barriers per quadrature.  j = t + 256k; j==0,1 -> t=0,1; j==999 -> t=231.
// Early-exit: (lo,hi) is a deterministic map; once it stops changing, all
// remaining bisection iterations are exact no-ops.
// ---------------------------------------------------------------------------
__global__ __launch_bounds__(256) void solve_scalars_kernel(
        const float* a, const float* b, const float* lc, float* ws) {
    __shared__ float pA[4], pB[4], spec[6];
    Co c = make_co(a, b, lc);
    int t = threadIdx.x;
    int lane = t & 63, w = t >> 6;

    // --- bisection 1: root of dL on [0.001, 0.999] ---
    float lo = 0.001f, hi = 0.999f;
    for (int it = 0; it < 30; ++it) {
        float mid = 0.5f * (lo + hi);
        Uni U = make_uni(c, mid);
        float sD = 0.f, d0 = 0.f, d1 = 0.f, dN = 0.f;
#pragma unroll
        for (int k = 0; k < 4; ++k) {
            int j = t + 256 * k;
            if (k < 3 || t < 232) {
                float y = fmaf((float)j, DYF, 0.001f);
                float u = 1.f - y * y;
                float iL, iD;
                point_LdL(c, U, y, u, iL, iD);
                sD += iD;
                if (k == 0) {
                    if (t == 0) d0 = iD;
                    if (t == 1) d1 = iD;
                }
                if (k == 3 && t == 231) dN = iD;
            }
        }
#pragma unroll
        for (int o = 32; o > 0; o >>= 1) sD += __shfl_xor(sD, o, 64);
        if (lane == 0) pB[w] = sD;
        if (t == 0)   spec[3] = d0;
        if (t == 1)   spec[4] = d1;
        if (t == 231) spec[5] = dN;
        __syncthreads();
        float SD = pB[0] + pB[1] + pB[2] + pB[3];
        float e0 = spec[3], e1 = spec[4], eN = spec[5];
        __syncthreads();   // epoch end: LDS reusable next iter
        float dL = trapz_ext(SD, e0, e1, eN) / PI_F;
        bool p = dL < 0.f;                 // fun(mid) < 0 -> hi = mid
        float nhi = p ? mid : hi;
        float nlo = p ? lo : mid;
        if (nlo == lo && nhi == hi) break; // fixed point: rest are no-ops
        lo = nlo; hi = nhi;
    }
    float zs_max = 0.5f * (lo + hi);

    // --- L_max at zs_max ---
    float L_max;
    {
        Uni U = make_uni(c, zs_max);
        float sL = 0.f, l0 = 0.f, l1 = 0.f, lN = 0.f;
#pragma unroll
        for (int k = 0; k < 4; ++k) {
            int j = t + 256 * k;
            if (k < 3 || t < 232) {
                float y = fmaf((float)j, DYF, 0.001f);
                float u = 1.f - y * y;
                float iL, iD;
                point_LdL(c, U, y, u, iL, iD);
                sL += iL;
                if (k == 0) {
                    if (t == 0) l0 = iL;
                    if (t == 1) l1 = iL;
                }
                if (k == 3 && t == 231) lN = iL;
            }
        }
#pragma unroll
        for (int o = 32; o > 0; o >>= 1) sL += __shfl_xor(sL, o, 64);
        if (lane == 0) pA[w] = sL;
        if (t == 0)   spec[0] = l0;
        if (t == 1)   spec[1] = l1;
        if (t == 231) spec[2] = lN;
        __syncthreads();
        float SL = pA[0] + pA[1] + pA[2] + pA[3];
        float i0 = spec[0], i1 = spec[1], iN = spec[2];
        __syncthreads();
        L_max = 4.f * zs_max * trapz_ext(SL, i0, i1, iN) / PI_F;
    }

    // --- bisection 2: root of -V on [0.001, zs_max] ---
    lo = 0.001f; hi = zs_max;
    for (int it = 0; it < 30; ++it) {
        float mid = 0.5f * (lo + hi);
        Uni U = make_uni(c, mid);
        float sc = 0.f, sd = 0.f;
        float c0 = 0.f, c1v = 0.f, cN = 0.f, q0 = 0.f, qN = 0.f;
#pragma unroll
        for (int k = 0; k < 4; ++k) {
            int j = t + 256 * k;
            if (k < 3 || t < 232) {
                float y = fmaf((float)j, DYF, 0.001f);
                float u = 1.f - y * y;
                float vc = point_Vc(c, U, y, u);
                float y2 = fmaf((float)j, DY2F, 0.001f);
                float vd = point_Vd(c, U, y2);
                sc += vc; sd += vd;
                if (k == 0) {
                    if (t == 0) { c0 = vc; q0 = vd; }
                    if (t == 1) { c1v = vc; }
                }
                if (k == 3 && t == 231) { cN = vc; qN = vd; }
            }
        }
#pragma unroll
        for (int o = 32; o > 0; o >>= 1) {
            sc += __shfl_xor(sc, o, 64);
            sd += __shfl_xor(sd, o, 64);
        }
        if (lane == 0) { pA[w] = sc; pB[w] = sd; }
        if (t == 0)   { spec[0] = c0; spec[3] = q0; }
        if (t == 1)   { spec[1] = c1v; }
        if (t == 231) { spec[2] = cN; spec[4] = qN; }
        __syncthreads();
        float Sc = pA[0] + pA[1] + pA[2] + pA[3];
        float Sd = pB[0] + pB[1] + pB[2] + pB[3];
        float i0 = spec[0], i1 = spec[1], iN = spec[2];
        float p0 = spec[3], pN = spec[4];
        __syncthreads();
        float Vc = c.coef * PI_F * 4.f * trapz_ext(Sc, i0, i1, iN) * frcp(mid);
        float Vd = c.coef * PI_F * 2.f * (1.f - mid) * trapz_d(Sd, p0, pN);
        bool p = (Vc - Vd) > 0.f;          // (-V) < 0 -> hi = mid
        float nhi = p ? mid : hi;
        float nlo = p ? lo : mid;
        if (nlo == lo && nhi == hi) break;
        lo = nlo; hi = nhi;
    }
    float zs_crit = 0.5f * (lo + hi);

    // --- L at zs_crit ---
    float L_crit;
    {
        Uni U = make_uni(c, zs_crit);
        float sL = 0.f, l0 = 0.f, l1 = 0.f, lN = 0.f;
#pragma unroll
        for (int k = 0; k < 4; ++k) {
            int j = t + 256 * k;
            if (k < 3 || t < 232) {
                float y = fmaf((float)j, DYF, 0.001f);
                float u = 1.f - y * y;
                float iL, iD;
                point_LdL(c, U, y, u, iL, iD);
                sL += iL;
                if (k == 0) {
                    if (t == 0) l0 = iL;
                    if (t == 1) l1 = iL;
                }
                if (k == 3 && t == 231) lN = iL;
            }
        }
#pragma unroll
        for (int o = 32; o > 0; o >>= 1) sL += __shfl_xor(sL, o, 64);
        if (lane == 0) pA[w] = sL;
        if (t == 0)   spec[0] = l0;
        if (t == 1)   spec[1] = l1;
        if (t == 231) spec[2] = lN;
        __syncthreads();
        float SL = pA[0] + pA[1] + pA[2] + pA[3];
        L_crit = 4.f * zs_crit * trapz_ext(SL, spec[0], spec[1], spec[2]) / PI_F;
    }

    if (t == 0) {
        ws[0] = zs_max; ws[1] = L_max; ws[2] = zs_crit; ws[3] = L_crit;
    }
}

// ---------------------------------------------------------------------------
// Kernel 2: per-element Newton + V.  One wave per element, 16 points/lane.
// NO min-waves launch bound: let the allocator take the VGPRs the unrolled
// body needs (the (256,4) bound capped it at 64 and spilled ~1.9 GB/call).
// j = lane + 64k; j==0,1 -> k=0 lanes 0,1;  j==999 -> k=15 lane 39.
// ---------------------------------------------------------------------------
__global__ __launch_bounds__(256) void newton_v_kernel(
        const float* Ls, const float* a, const float* b, const float* lc,
        const float* ws, float* out, int B) {
    int wid = (blockIdx.x * blockDim.x + threadIdx.x) >> 6;
    int lane = threadIdx.x & 63;
    if (wid >= B) return;

    Co c = make_co(a, b, lc);
    float zs_max = ws[0], L_max = ws[1], L_crit = ws[3];
    float Lq = Ls[wid];
    bool valid = Lq < L_crit;
    float L_eff = valid ? Lq : 0.5f * L_crit;
    float zs = fminf(fmaxf(L_eff * frcp(L_max) * zs_max, 1e-4f), 0.9995f);
    float zs_prev = -1.f;

    for (int step = 0; step < 25; ++step) {
        Uni U = make_uni(c, zs);
        float sL = 0.f, sD = 0.f, l0 = 0.f, d0 = 0.f, lN = 0.f, dN = 0.f;
#pragma unroll
        for (int k = 0; k < 16; ++k) {
            if (k < 15 || lane < 40) {     // j < 1000; constant-true for k<15
                int j = lane + 64 * k;
                float y = fmaf((float)j, DYF, 0.001f);
                float u = 1.f - y * y;
                float iL, iD;
                point_LdL(c, U, y, u, iL, iD);
                sL += iL; sD += iD;
                if (k == 0)  { l0 = iL; d0 = iD; }
                if (k == 15) { lN = iL; dN = iD; }
            }
        }
#pragma unroll
        for (int o = 32; o > 0; o >>= 1) {
            sL += __shfl_xor(sL, o, 64);
            sD += __shfl_xor(sD, o, 64);
        }
        float i0 = __shfl(l0, 0, 64), i1 = __shfl(l0, 1, 64), iN = __shfl(lN, 39, 64);
        float e0 = __shfl(d0, 0, 64), e1 = __shfl(d0, 1, 64), eN = __shfl(dN, 39, 64);
        float Lz = 4.f * zs * trapz_ext(sL, i0, i1, iN) / PI_F;
        float dL = trapz_ext(sD, e0, e1, eN) / PI_F;
        float nzs = fminf(fmaxf(zs - (Lz - L_eff) * frcp(dL), 1e-4f), 0.9995f);
        if (nzs == zs || nzs == zs_prev) break;   // fixed point or 2-cycle
        zs_prev = zs;
        zs = nzs;
    }

    // V(zs)
    Uni U = make_uni(c, zs);
    float sc = 0.f, sd = 0.f, c0 = 0.f, cN = 0.f, q0 = 0.f, qN = 0.f;
#pragma unroll
    for (int k = 0; k < 16; ++k) {
        if (k < 15 || lane < 40) {
            int j = lane + 64 * k;
            float y = fmaf((float)j, DYF, 0.001f);
            float u = 1.f - y * y;
            float vc = point_Vc(c, U, y, u);
            float y2 = fmaf((float)j, DY2F, 0.001f);
            float vd = point_Vd(c, U, y2);
            sc += vc; sd += vd;
            if (k == 0)  { c0 = vc; q0 = vd; }
            if (k == 15) { cN = vc; qN = vd; }
        }
    }
#pragma unroll
    for (int o = 32; o > 0; o >>= 1) {
        sc += __shfl_xor(sc, o, 64);
        sd += __shfl_xor(sd, o, 64);
    }
    float i0 = __shfl(c0, 0, 64), i1 = __shfl(c0, 1, 64), iN = __shfl(cN, 39, 64);
    float p0 = __shfl(q0, 0, 64), pN = __shfl(qN, 39, 64);
    float Vc = c.coef * PI_F * 4.f * trapz_ext(sc, i0, i1, iN) * frcp(zs);
    float Vd = c.coef * PI_F * 2.f * (1.f - zs) * trapz_d(sd, p0, pN);

    if (lane == 0) out[wid] = valid ? (Vc - Vd) : 0.f;
}

// ---------------------------------------------------------------------------
extern "C" void kernel_launch(void* const* d_in, const int* in_sizes, int n_in,
                              void* d_out, int out_size, void* d_ws, size_t ws_size,
                              hipStream_t stream) {
    const float* Ls = (const float*)d_in[0];
    const float* a  = (const float*)d_in[1];
    const float* b  = (const float*)d_in[2];
    const float* lc = (const float*)d_in[3];
    float* out = (float*)d_out;
    float* ws  = (float*)d_ws;
    int B = in_sizes[0];

    solve_scalars_kernel<<<1, 256, 0, stream>>>(a, b, lc, ws);

    int blocks = (B + 3) / 4;   // 4 waves (elements) per 256-thread block
    newton_v_kernel<<<blocks, 256, 0, stream>>>(Ls, a, b, lc, ws, out, B);
}